// Round 2
// 313.454 us; speedup vs baseline: 1.0041x; 1.0041x over previous
//
#include <hip/hip_runtime.h>
#include <math.h>
#include <stdint.h>

#define BATCH 2
#define SEQ   1024
#define EMB   1024
#define NH    16
#define DH    64
#define BSE   (BATCH*SEQ*EMB)   /* 2097152 elements per (B,S,E) tensor */
#define MROWS (BATCH*SEQ)       /* 2048 */

typedef unsigned short u16;
typedef __attribute__((ext_vector_type(8))) short short8;
typedef __attribute__((ext_vector_type(4))) float f32x4;

__device__ __forceinline__ float bf2f(u16 u) {
    return __uint_as_float(((unsigned int)u) << 16);
}
__device__ __forceinline__ u16 f2bf(float f) {
    unsigned int x = __float_as_uint(f);
    x += 0x7FFFu + ((x >> 16) & 1u);   // round-to-nearest-even
    return (u16)(x >> 16);
}

__device__ __forceinline__ void async_copy16(const void* g, void* l) {
    __builtin_amdgcn_global_load_lds(
        (const __attribute__((address_space(1))) unsigned int*)g,
        (__attribute__((address_space(3))) unsigned int*)l,
        16, 0, 0);
}

#define VMCNT(N)  asm volatile("s_waitcnt vmcnt(" #N ")" ::: "memory")
#define BARRIER_SYNC() do { asm volatile("" ::: "memory"); \
                            __builtin_amdgcn_s_barrier();  \
                            asm volatile("" ::: "memory"); } while (0)

// ---------------------------------------------------------------------------
// Pack: fp32 -> bf16, 20 slots of exactly 1M elems each (no idle blocks).
// ---------------------------------------------------------------------------
struct PackArgs {
    const float* src[20];
    u16*         dst[20];
    int          scaled[20];
};

__global__ __launch_bounds__(256) void pack_kernel(PackArgs pa, const float* __restrict__ theta)
{
    const int e = blockIdx.y;
    const size_t i = ((size_t)blockIdx.x * 256 + threadIdx.x) * 4;
    float sc = 1.0f;
    if (pa.scaled[e]) sc = sinf(2.0f * theta[0]) - 1.0f;
    float4 v = *(const float4*)(pa.src[e] + i);
    ushort4 o;
    o.x = f2bf(v.x * sc); o.y = f2bf(v.y * sc);
    o.z = f2bf(v.z * sc); o.w = f2bf(v.w * sc);
    *(ushort4*)(pa.dst[e] + i) = o;
}

// ---------------------------------------------------------------------------
// QKV projection GEMM: 256x256 tile, BK=64, 8 waves, 8-phase schedule with
// counted vmcnt (T3+T4), XOR chunk swizzle (T2), setprio (T5).
// Virtual K-concat (K=2048 = A1|A2 x Blo|Bhi). 24 n-tiles over 6 segments.
//   mode 0: bf16 [m][c] store; mode 2: bf16 transposed [b][c][s] (V^T).
//
// Staging order per tile kt (issued during tile kt-1's phases p0..p3):
//   A-lo, B-lo, B-hi, A-hi  (2 global_load_lds calls each)
// Phase quadrants: p0=(0,0) p1=(0,1) p2=(1,1) p3=(1,0); p3 reads nothing
// (keeps B-lo frags in regs), so steady-state waits are vmcnt(6) at
// p0/p1/p2 only, and the final tile drains 4 -> 2 -> 0.
// ---------------------------------------------------------------------------
struct Gemm8Args {
    const u16*   A1s[6];
    const u16*   A2s[6];
    const u16*   Blo[6];
    const u16*   Bhi[6];
    const float* bias[6];
    void*        dst[6];
    int          mode[6];
};

__global__ __launch_bounds__(512, 2) void mfma_gemm8(Gemm8Args ga)
{
    __shared__ u16 lds[2][2][256][64];   // [buf][A/B][row][col] = 128 KiB

    const int t    = threadIdx.x;
    const int lane = t & 63;
    const int w    = t >> 6;
    const int wm   = w >> 2;       // 0..1
    const int wn   = w & 3;        // 0..3
    const int L15  = lane & 15;
    const int quad = lane >> 4;
    const int rswz = L15 & 7;      // read-side chunk swizzle key

    // XCD-aware bijective mapping: XCD x = bid&7 gets nt in [3x,3x+3), all mt.
    const int bid = blockIdx.x;
    const int xcd = bid & 7;
    const int idx = bid >> 3;            // 0..23
    const int nt  = xcd * 3 + (idx >> 3);
    const int mt  = idx & 7;
    const int m0   = mt * 256;
    const int seg  = nt >> 2;
    const int nloc = (nt & 3) * 256;

    const char* A1 = (const char*)ga.A1s[seg];
    const char* A2 = (const char*)ga.A2s[seg];
    const char* Bl = (const char*)ga.Blo[seg];
    const char* Bh = (const char*)ga.Bhi[seg];

    // staging: thread t covers row t>>3 (of a 64-row call), chunk t&7.
    // source chunk pre-swizzled: chunk ^ (row&7); LDS dest stays linear.
    const int   srow8 = t >> 3;
    const int   g16   = (((t & 7) ^ (srow8 & 7)) << 4);
    const char* A1t = A1 + (size_t)(m0   + srow8) * 2048 + g16;
    const char* A2t = A2 + (size_t)(m0   + srow8) * 2048 + g16;
    const char* Blt = Bl + (size_t)(nloc + srow8) * 2048 + g16;
    const char* Bht = Bh + (size_t)(nloc + srow8) * 2048 + g16;
    char* ldsW = (char*)&lds[0][0][0][0] + w * 1024;   // wave's 8-row slab

    auto stage_half = [&](int buf, int mat, const char* srcT, size_t kcol, int r0) {
        #pragma unroll
        for (int c = 0; c < 2; ++c)
            async_copy16(srcT + (size_t)(r0 + c*64) * 2048 + kcol,
                         ldsW + buf*65536 + mat*32768 + (r0 + c*64)*128);
    };

    auto ldA = [&](const u16* Abw, int mq, int m, int ks) -> short8 {
        return *(const short8*)(Abw + (mq*128 + m*16)*64 + (((ks*4 + quad) ^ rswz) << 3));
    };
    auto ldB = [&](const u16* Bbw, int nq, int n, int ks) -> short8 {
        return *(const short8*)(Bbw + (nq*128 + n*16)*64 + (((ks*4 + quad) ^ rswz) << 3));
    };

    f32x4 acc00[4][2] = {};
    f32x4 acc01[4][2] = {};
    f32x4 acc11[4][2] = {};
    f32x4 acc10[4][2] = {};
    short8 fa[4][2];    // A-frags of current m-half
    short8 fb0[2][2];   // B nq=0 (kept across whole tile)
    short8 fb1[2][2];   // B nq=1

    auto mfma4x2 = [&](f32x4 (&accq)[4][2], short8 (&a)[4][2], short8 (&b)[2][2]) {
        __builtin_amdgcn_s_setprio(1);
        #pragma unroll
        for (int m = 0; m < 4; ++m)
            #pragma unroll
            for (int n = 0; n < 2; ++n) {
                accq[m][n] = __builtin_amdgcn_mfma_f32_16x16x32_bf16(a[m][0], b[n][0], accq[m][n], 0, 0, 0);
                accq[m][n] = __builtin_amdgcn_mfma_f32_16x16x32_bf16(a[m][1], b[n][1], accq[m][n], 0, 0, 0);
            }
        __builtin_amdgcn_s_setprio(0);
    };

    // ---- prologue: tile 0 into buf 0 (issue order = A-lo, B-lo, B-hi, A-hi)
    stage_half(0, 0, A1t, 0, 0);
    stage_half(0, 1, Blt, 0, 0);
    stage_half(0, 1, Blt, 0, 128);
    stage_half(0, 0, A1t, 0, 128);

    // ---- main loop: tiles 0..30 steady state, tile 31 peeled ----
    for (int kt = 0; kt < 31; ++kt) {
        const int cur = kt & 1, nxt = cur ^ 1;
        const bool hi = ((kt + 1) & 16) != 0;
        const char* At = hi ? A2t : A1t;
        const char* Bt = hi ? Bht : Blt;
        const size_t kc = (size_t)((kt + 1) & 15) * 128;
        const u16* Abw = &lds[cur][0][wm*64 + L15][0];
        const u16* Bbw = &lds[cur][1][wn*32 + L15][0];

        // ---- p0: quadrant (0,0) ----
        stage_half(nxt, 0, At, kc, 0);           // A-lo(kt+1)
        VMCNT(6);
        BARRIER_SYNC();
        #pragma unroll
        for (int m = 0; m < 4; ++m)
            #pragma unroll
            for (int ks = 0; ks < 2; ++ks)
                fa[m][ks] = ldA(Abw, 0, m, ks);
        #pragma unroll
        for (int n = 0; n < 2; ++n)
            #pragma unroll
            for (int ks = 0; ks < 2; ++ks)
                fb0[n][ks] = ldB(Bbw, 0, n, ks);
        mfma4x2(acc00, fa, fb0);

        // ---- p1: quadrant (0,1) ----
        stage_half(nxt, 1, Bt, kc, 0);           // B-lo(kt+1)
        VMCNT(6);
        BARRIER_SYNC();
        #pragma unroll
        for (int n = 0; n < 2; ++n)
            #pragma unroll
            for (int ks = 0; ks < 2; ++ks)
                fb1[n][ks] = ldB(Bbw, 1, n, ks);
        mfma4x2(acc01, fa, fb1);

        // ---- p2: quadrant (1,1) ----
        stage_half(nxt, 1, Bt, kc, 128);         // B-hi(kt+1)
        VMCNT(6);
        BARRIER_SYNC();
        #pragma unroll
        for (int m = 0; m < 4; ++m)
            #pragma unroll
            for (int ks = 0; ks < 2; ++ks)
                fa[m][ks] = ldA(Abw, 1, m, ks);
        mfma4x2(acc11, fa, fb1);

        // ---- p3: quadrant (1,0) — no reads, no barrier ----
        stage_half(nxt, 0, At, kc, 128);         // A-hi(kt+1)
        mfma4x2(acc10, fa, fb0);
    }

    // ---- peeled last tile (kt=31, buf 1): drains 4 -> 2 -> 0 ----
    {
        const u16* Abw = &lds[1][0][wm*64 + L15][0];
        const u16* Bbw = &lds[1][1][wn*32 + L15][0];

        VMCNT(4);
        BARRIER_SYNC();
        #pragma unroll
        for (int m = 0; m < 4; ++m)
            #pragma unroll
            for (int ks = 0; ks < 2; ++ks)
                fa[m][ks] = ldA(Abw, 0, m, ks);
        #pragma unroll
        for (int n = 0; n < 2; ++n)
            #pragma unroll
            for (int ks = 0; ks < 2; ++ks)
                fb0[n][ks] = ldB(Bbw, 0, n, ks);
        mfma4x2(acc00, fa, fb0);

        VMCNT(2);
        BARRIER_SYNC();
        #pragma unroll
        for (int n = 0; n < 2; ++n)
            #pragma unroll
            for (int ks = 0; ks < 2; ++ks)
                fb1[n][ks] = ldB(Bbw, 1, n, ks);
        mfma4x2(acc01, fa, fb1);

        VMCNT(0);
        BARRIER_SYNC();
        #pragma unroll
        for (int m = 0; m < 4; ++m)
            #pragma unroll
            for (int ks = 0; ks < 2; ++ks)
                fa[m][ks] = ldA(Abw, 1, m, ks);
        mfma4x2(acc11, fa, fb1);

        mfma4x2(acc10, fa, fb0);
    }

    // ---- epilogue: C layout col = L15 (+n*16), row = quad*4+reg (+m*16) ----
    const float* bias = ga.bias[seg];
    const int mode = ga.mode[seg];
    u16* dst = (u16*)ga.dst[seg];

    auto store_quad = [&](f32x4 (&accq)[4][2], int mq, int nq) {
        #pragma unroll
        for (int n = 0; n < 2; ++n) {
            const int c = nloc + nq*128 + wn*32 + n*16 + L15;
            const float bv = bias[c];
            #pragma unroll
            for (int m = 0; m < 4; ++m) {
                #pragma unroll
                for (int reg = 0; reg < 4; ++reg) {
                    const int row = m0 + mq*128 + wm*64 + m*16 + quad*4 + reg;
                    const float val = accq[m][n][reg] + bv;
                    if (mode == 2) {
                        // V^T: [b][c][s]
                        dst[((size_t)(row >> 10) << 20) + (size_t)c*1024 + (row & 1023)] = f2bf(val);
                    } else {
                        dst[(size_t)row*1024 + c] = f2bf(val);
                    }
                }
            }
        }
    };
    store_quad(acc00, 0, 0);
    store_quad(acc01, 0, 1);
    store_quad(acc11, 1, 1);
    store_quad(acc10, 1, 0);
}

// ---------------------------------------------------------------------------
// Legacy 128x128 MFMA GEMM (kept for the O-projection, split-K=2).
// ---------------------------------------------------------------------------
struct GemmArgs {
    const u16*   A1s[8];
    const u16*   A2s[8];
    const u16*   Blo[8];
    const u16*   Bhi[8];
    const float* bias[8];
    void*        dst[8];
    int          mode[8];
};

template<int SPLITK>
__global__ __launch_bounds__(256) void mfma_gemm(GemmArgs ga)
{
    __shared__ u16 sA[128][32];
    __shared__ u16 sB[128][32];

    const int t    = threadIdx.x;
    const int lane = t & 63;
    const int w    = t >> 6;
    const int wx   = w & 1;
    const int wy   = w >> 1;
    const int n0   = blockIdx.y * 128;
    const int m0   = blockIdx.x * 128;
    const int ko   = (SPLITK == 2) ? blockIdx.z : 0;
    const int seg  = n0 >> 10;
    const int nloc = n0 & 1023;

    const int srow = t >> 2;
    const int sb   = (t & 3) * 16;

    f32x4 acc[4][4] = {};

    const char* A1 = (const char*)ga.A1s[seg];
    const char* A2 = (const char*)ga.A2s[seg];
    const char* Bl = (const char*)ga.Blo[seg];
    const char* Bh = (const char*)ga.Bhi[seg];
    if (SPLITK == 2 && ko) { A1 = A2; Bl = Bh; }

    const int frow = lane & 15;
    const int quad = lane >> 4;

    const int NKT = (SPLITK == 2) ? 32 : 64;
    for (int kt = 0; kt < NKT; ++kt) {
        const char* As = (SPLITK == 1 && (kt & 32)) ? A2 : A1;
        const char* Bs = (SPLITK == 1 && (kt & 32)) ? Bh : Bl;
        const size_t kbyte = (size_t)(kt & 31) * 64;

        __syncthreads();
        #pragma unroll
        for (int r = 0; r < 2; ++r) {
            const int row = r*64 + srow;
            const int ldsoff = (r*64 + w*16) * 64;
            async_copy16(As + (size_t)(m0 + row)*2048 + kbyte + sb,
                         (char*)&sA[0][0] + ldsoff);
            async_copy16(Bs + (size_t)(nloc + row)*2048 + kbyte + sb,
                         (char*)&sB[0][0] + ldsoff);
        }
        __syncthreads();

        short8 af[4], bfr[4];
        #pragma unroll
        for (int i = 0; i < 4; ++i)
            af[i] = *(const short8*)&sA[wy*64 + i*16 + frow][quad*8];
        #pragma unroll
        for (int j = 0; j < 4; ++j)
            bfr[j] = *(const short8*)&sB[wx*64 + j*16 + frow][quad*8];

        #pragma unroll
        for (int i = 0; i < 4; ++i)
            #pragma unroll
            for (int j = 0; j < 4; ++j)
                acc[i][j] = __builtin_amdgcn_mfma_f32_16x16x32_bf16(
                                af[i], bfr[j], acc[i][j], 0, 0, 0);
    }

    const float* bias = ga.bias[seg];
    const int mode = ga.mode[seg];

    #pragma unroll
    for (int j = 0; j < 4; ++j) {
        const int c = nloc + wx*64 + j*16 + frow;
        const float bv = (SPLITK == 2 && ko) ? 0.0f : bias[c];
        #pragma unroll
        for (int i = 0; i < 4; ++i) {
            #pragma unroll
            for (int reg = 0; reg < 4; ++reg) {
                const int m = m0 + wy*64 + i*16 + quad*4 + reg;
                const float val = acc[i][j][reg] + bv;
                if (mode == 1) {
                    if (SPLITK == 2)
                        atomicAdd((float*)ga.dst[seg] + (size_t)m*1024 + c, val);
                    else
                        ((float*)ga.dst[seg])[(size_t)m*1024 + c] = val;
                } else if (mode == 2) {
                    ((u16*)ga.dst[seg])[((size_t)(m >> 10) << 20) + (size_t)c*1024 + (m & 1023)] = f2bf(val);
                } else {
                    ((u16*)ga.dst[seg])[(size_t)m*1024 + c] = f2bf(val);
                }
            }
        }
    }
}

// ---------------------------------------------------------------------------
// RoPE, in place on (B,S,E) bf16; pair (d, d+32) within each head.
// ---------------------------------------------------------------------------
__global__ __launch_bounds__(256) void rope_kernel(
    u16* qa, u16* qb, u16* ka, u16* kb)
{
    u16* p;
    switch (blockIdx.y) {
        case 0:  p = qa; break;
        case 1:  p = qb; break;
        case 2:  p = ka; break;
        default: p = kb; break;
    }
    const int i   = blockIdx.x * 256 + threadIdx.x;
    const int d   = i & 31;
    const int hh  = (i >> 5) & (NH - 1);
    const int row = i >> 9;
    const int s   = row & (SEQ - 1);
    const size_t base = (size_t)row * EMB + hh * DH;

    float x1 = bf2f(p[base + d]);
    float x2 = bf2f(p[base + d + 32]);
    const float invf_rev = expf(-(float)d * 0.28782313662425576f) * 0.15915494309189535f;
    float rev = (float)s * invf_rev;
    rev -= floorf(rev);
    const float sn = __builtin_amdgcn_sinf(rev);
    const float cs = __builtin_amdgcn_cosf(rev);
    p[base + d]      = f2bf(x1 * cs - x2 * sn);
    p[base + d + 32] = f2bf(x2 * cs + x1 * sn);
}

// ---------------------------------------------------------------------------
// MFMA flash attention, fixed-max softmax.
// ---------------------------------------------------------------------------
__global__ __launch_bounds__(256) void attn_mfma(
    const u16* __restrict__ qa, const u16* __restrict__ qb,
    const u16* __restrict__ ka, const u16* __restrict__ kb,
    const u16* __restrict__ vat, const u16* __restrict__ vbt,
    const float* __restrict__ thetas,
    u16* __restrict__ oa, u16* __restrict__ ob)
{
    __shared__ u16 sKa[64][64];
    __shared__ u16 sKb[64][64];
    __shared__ u16 sVa[64][64];
    __shared__ u16 sVb[64][64];
    __shared__ u16 sP[4][16][72];

    const int t    = threadIdx.x;
    const int lane = t & 63;
    const int w    = t >> 6;
    const int L15  = lane & 15;
    const int quad = lane >> 4;

    const int bid  = blockIdx.x;
    const int aa   = (bid >> 5) & 7;
    const int qt   = (bid >> 8) ? aa : (15 - aa);
    const int bh   = bid & 31;
    const int h    = bh & 15;
    const int b    = bh >> 4;

    const float j2h = sinf(2.0f * thetas[h]) - 1.0f;

    const int   qrow  = qt*64 + w*16 + L15;
    const size_t qbase = (size_t)(b*SEQ + qrow) * EMB + h*DH;
    short8 fqa[2], fqb[2], fjqb[2];
    fqa[0] = *(const short8*)(qa + qbase + quad*8);
    fqa[1] = *(const short8*)(qa + qbase + 32 + quad*8);
    fqb[0] = *(const short8*)(qb + qbase + quad*8);
    fqb[1] = *(const short8*)(qb + qbase + 32 + quad*8);
    #pragma unroll
    for (int s2 = 0; s2 < 2; ++s2) {
        short8 src = fqb[s2], dst;
        #pragma unroll
        for (int j = 0; j < 8; ++j)
            dst[j] = (short)f2bf(bf2f((u16)src[j]) * j2h);
        fjqb[s2] = dst;
    }

    f32x4 acc_a[4] = {};
    f32x4 acc_b[4] = {};
    float l_lane[4] = {0.f, 0.f, 0.f, 0.f};

    const int subrow = lane >> 3;
    const int g      = (lane & 7) ^ subrow;
    const int swz    = L15 & 7;

    for (int kt = 0; kt <= qt; ++kt) {
        __syncthreads();
        #pragma unroll
        for (int i = 0; i < 2; ++i) {
            const int row = w*16 + i*8 + subrow;
            const int ldsoff = (w*16 + i*8) * 128;
            const size_t ktok = (size_t)(b*SEQ + kt*64 + row);
            async_copy16((const char*)ka + ktok*2048 + h*128 + g*16,
                         (char*)&sKa[0][0] + ldsoff);
            async_copy16((const char*)kb + ktok*2048 + h*128 + g*16,
                         (char*)&sKb[0][0] + ldsoff);
            const size_t vrow = (size_t)b*1048576 + (size_t)(h*64 + row)*1024 + kt*64;
            async_copy16((const char*)vat + vrow*2 + g*16,
                         (char*)&sVa[0][0] + ldsoff);
            async_copy16((const char*)vbt + vrow*2 + g*16,
                         (char*)&sVb[0][0] + ldsoff);
        }
        __syncthreads();

        f32x4 sa[4] = {}, sb[4] = {};
        #pragma unroll
        for (int n = 0; n < 4; ++n) {
            const u16* rKa = &sKa[n*16 + L15][0];
            const u16* rKb = &sKb[n*16 + L15][0];
            short8 ka0 = *(const short8*)(rKa + (( quad      ^ swz) << 3));
            short8 ka1 = *(const short8*)(rKa + (((4 + quad) ^ swz) << 3));
            short8 kb0 = *(const short8*)(rKb + (( quad      ^ swz) << 3));
            short8 kb1 = *(const short8*)(rKb + (((4 + quad) ^ swz) << 3));
            sa[n] = __builtin_amdgcn_mfma_f32_16x16x32_bf16(fqa[0],  ka0, sa[n], 0, 0, 0);
            sa[n] = __builtin_amdgcn_mfma_f32_16x16x32_bf16(fqa[1],  ka1, sa[n], 0, 0, 0);
            sa[n] = __builtin_amdgcn_mfma_f32_16x16x32_bf16(fjqb[0], kb0, sa[n], 0, 0, 0);
            sa[n] = __builtin_amdgcn_mfma_f32_16x16x32_bf16(fjqb[1], kb1, sa[n], 0, 0, 0);
            sb[n] = __builtin_amdgcn_mfma_f32_16x16x32_bf16(fqa[0],  kb0, sb[n], 0, 0, 0);
            sb[n] = __builtin_amdgcn_mfma_f32_16x16x32_bf16(fqa[1],  kb1, sb[n], 0, 0, 0);
            sb[n] = __builtin_amdgcn_mfma_f32_16x16x32_bf16(fqb[0],  ka0, sb[n], 0, 0, 0);
            sb[n] = __builtin_amdgcn_mfma_f32_16x16x32_bf16(fqb[1],  ka1, sb[n], 0, 0, 0);
        }

        float p[4][4];
        if (kt == qt) {
            #pragma unroll
            for (int n = 0; n < 4; ++n)
                #pragma unroll
                for (int r = 0; r < 4; ++r) {
                    const float A = sa[n][r], B = sb[n][r];
                    const float mag = __builtin_amdgcn_sqrtf(A*A + B*B + 1e-8f) * 0.125f;
                    const bool masked = (n*16 + L15) > (w*16 + quad*4 + r);
                    p[n][r] = masked ? 0.0f
                                     : __builtin_amdgcn_exp2f(mag * 1.44269504f);
                }
        } else {
            #pragma unroll
            for (int n = 0; n < 4; ++n)
                #pragma unroll
                for (int r = 0; r < 4; ++r) {
                    const float A = sa[n][r], B = sb[n][r];
                    const float mag = __builtin_amdgcn_sqrtf(A*A + B*B + 1e-8f) * 0.125f;
                    p[n][r] = __builtin_amdgcn_exp2f(mag * 1.44269504f);
                }
        }
        #pragma unroll
        for (int r = 0; r < 4; ++r)
            l_lane[r] += (p[0][r] + p[1][r]) + (p[2][r] + p[3][r]);

        #pragma unroll
        for (int n = 0; n < 4; ++n)
            #pragma unroll
            for (int r = 0; r < 4; ++r)
                sP[w][quad*4 + r][n*16 + L15] = f2bf(p[n][r]);

        short8 pf0 = *(const short8*)&sP[w][L15][quad*8];
        short8 pf1 = *(const short8*)&sP[w][L15][32 + quad*8];

        #pragma unroll
        for (int n = 0; n < 4; ++n) {
            const u16* rVa = &sVa[n*16 + L15][0];
            const u16* rVb = &sVb[n*16 + L15][0];
            short8 va0 = *(const short8*)(rVa + (( quad      ^ swz) << 3));
            short8 va1 = *(const short8*)(rVa + (((4 + quad) ^ swz) << 3));
            short8 vb0 = *(const short8*)(rVb + (( quad      ^ swz) << 3));
            short8 vb1 = *(const short8*)(rVb + (((4 + quad) ^ swz) << 3));
            acc_a[n] = __builtin_amdgcn_mfma_f32_16x16x32_bf16(pf0, va0, acc_a[n], 0, 0, 0);
            acc_a[n] = __builtin_amdgcn_mfma_f32_16x16x32_bf16(pf1, va1, acc_a[n], 0, 0, 0);
            acc_b[n] = __builtin_amdgcn_mfma_f32_16x16x32_bf16(pf0, vb0, acc_b[n], 0, 0, 0);
            acc_b[n] = __builtin_amdgcn_mfma_f32_16x16x32_bf16(pf1, vb1, acc_b[n], 0, 0, 0);
        }
    }

    float inv[4];
    #pragma unroll
    for (int r = 0; r < 4; ++r) {
        float l = l_lane[r];
        #pragma unroll
        for (int off = 8; off >= 1; off >>= 1)
            l += __shfl_xor(l, off, 64);
        inv[r] = 1.0f / l;
    }

    #pragma unroll
    for (int reg = 0; reg < 4; ++reg) {
        const size_t tok = (size_t)(b*SEQ + qt*64 + w*16 + quad*4 + reg);
        #pragma unroll
        for (int n = 0; n < 4; ++n) {
            const size_t idx = tok*EMB + h*DH + n*16 + L15;
            oa[idx] = f2bf(acc_a[n][reg] * inv[reg]);
            ob[idx] = f2bf(acc_b[n][reg] * inv[reg]);
        }
    }
}

// ---------------------------------------------------------------------------
extern "C" void kernel_launch(void* const* d_in, const int* in_sizes, int n_in,
                              void* d_out, int out_size, void* d_ws, size_t ws_size,
                              hipStream_t stream)
{
    const float* x_q_a  = (const float*)d_in[0];
    const float* x_q_b  = (const float*)d_in[1];
    const float* x_kv_a = (const float*)d_in[2];
    const float* x_kv_b = (const float*)d_in[3];
    const float* theta    = (const float*)d_in[5];
    const float* thetas_h = (const float*)d_in[6];
    const float* q_wa = (const float*)d_in[7];
    const float* q_wb = (const float*)d_in[8];
    const float* q_ba = (const float*)d_in[9];
    const float* q_bb = (const float*)d_in[10];
    const float* k_wa = (const float*)d_in[11];
    const float* k_wb = (const float*)d_in[12];
    const float* k_ba = (const float*)d_in[13];
    const float* k_bb = (const float*)d_in[14];
    const float* v_wa = (const float*)d_in[15];
    const float* v_wb = (const float*)d_in[16];
    const float* v_ba = (const float*)d_in[17];
    const float* v_bb = (const float*)d_in[18];
    const float* o_wa = (const float*)d_in[19];
    const float* o_wb = (const float*)d_in[20];
    const float* o_ba = (const float*)d_in[21];
    const float* o_bb = (const float*)d_in[22];

    u16* W = (u16*)d_ws;
    const size_t XN = (size_t)BSE;
    const size_t WN = (size_t)EMB*EMB;
    u16* xq_a16  = W;
    u16* xq_b16  = W + XN;
    u16* xkv_a16 = W + 2*XN;
    u16* xkv_b16 = W + 3*XN;
    u16* wbase   = W + 4*XN;
    u16* q_wa16  = wbase;
    u16* q_wb16  = wbase + WN;
    u16* k_wa16  = wbase + 2*WN;
    u16* k_wb16  = wbase + 3*WN;
    u16* v_wa16  = wbase + 4*WN;
    u16* v_wb16  = wbase + 5*WN;
    u16* o_wa16  = wbase + 6*WN;
    u16* o_wb16  = wbase + 7*WN;
    u16* q_wbs16 = wbase + 8*WN;
    u16* k_wbs16 = wbase + 9*WN;
    u16* v_wbs16 = wbase + 10*WN;
    u16* o_wbs16 = wbase + 11*WN;
    u16* qkv     = wbase + 12*WN;
    u16* qa16 = qkv;
    u16* qb16 = qkv + XN;
    u16* ka16 = qkv + 2*XN;
    u16* kb16 = qkv + 3*XN;
    u16* vat16 = qkv + 4*XN;   // transposed [b][c][s]
    u16* vbt16 = qkv + 5*XN;
    u16* ao16 = xq_a16;        // alias: xq region free after QKV GEMM
    u16* bo16 = xq_b16;

    float* out_a = (float*)d_out;
    float* out_b = out_a + (size_t)BSE;

    // ---- 1. pack to bf16 ----
    PackArgs pa;
    int si = 0;
    auto add = [&](const float* s, u16* d, int scaled, int chunks) {
        for (int c = 0; c < chunks; ++c) {
            pa.src[si] = s + (size_t)c * WN;
            pa.dst[si] = d + (size_t)c * WN;
            pa.scaled[si] = scaled;
            ++si;
        }
    };
    add(x_q_a,  xq_a16,  0, 2);
    add(x_q_b,  xq_b16,  0, 2);
    add(x_kv_a, xkv_a16, 0, 2);
    add(x_kv_b, xkv_b16, 0, 2);
    add(q_wa, q_wa16, 0, 1);  add(q_wb, q_wb16, 0, 1);
    add(k_wa, k_wa16, 0, 1);  add(k_wb, k_wb16, 0, 1);
    add(v_wa, v_wa16, 0, 1);  add(v_wb, v_wb16, 0, 1);
    add(o_wa, o_wa16, 0, 1);  add(o_wb, o_wb16, 0, 1);
    add(q_wb, q_wbs16, 1, 1); add(k_wb, k_wbs16, 1, 1);
    add(v_wb, v_wbs16, 1, 1); add(o_wb, o_wbs16, 1, 1);
    pack_kernel<<<dim3(WN/1024, 20), 256, 0, stream>>>(pa, theta);

    hipMemsetAsync(d_out, 0, (size_t)out_size * sizeof(float), stream);

    // ---- 2. QKV projections: 8-phase 256x256 kernel, 24 n-tiles ----
    Gemm8Args g8;
    {
        const u16* a1s[6] = { xq_a16, xq_a16, xkv_a16, xkv_a16, xkv_a16, xkv_a16 };
        const u16* a2s[6] = { xq_b16, xq_b16, xkv_b16, xkv_b16, xkv_b16, xkv_b16 };
        const u16* blo[6] = { q_wa16, q_wb16, k_wa16, k_wb16, v_wa16, v_wb16 };
        const u16* bhi[6] = { q_wbs16, q_wa16, k_wbs16, k_wa16, v_wbs16, v_wa16 };
        const float* bia[6] = { q_ba, q_bb, k_ba, k_bb, v_ba, v_bb };
        void* dsts[6] = { qa16, qb16, ka16, kb16, vat16, vbt16 };
        const int modes[6] = { 0, 0, 0, 0, 2, 2 };
        for (int s = 0; s < 6; ++s) {
            g8.A1s[s] = a1s[s]; g8.A2s[s] = a2s[s];
            g8.Blo[s] = blo[s]; g8.Bhi[s] = bhi[s];
            g8.bias[s] = bia[s]; g8.dst[s] = dsts[s]; g8.mode[s] = modes[s];
        }
    }
    mfma_gemm8<<<dim3(192), 512, 0, stream>>>(g8);

    // ---- 3. RoPE (q/k) ----
    rope_kernel<<<dim3((BATCH*SEQ*NH*32)/256, 4), 256, 0, stream>>>(qa16, qb16, ka16, kb16);

    // ---- 4. attention ----
    attn_mfma<<<BATCH*NH*(SEQ/64), 256, 0, stream>>>(qa16, qb16, ka16, kb16,
                                                     vat16, vbt16, thetas_h, ao16, bo16);

    // ---- 5. output projection: split-K=2, fp32 atomic accumulation ----
    GemmArgs g3;
    for (int s = 0; s < 8; ++s) {
        g3.A1s[s] = ao16; g3.A2s[s] = bo16;
        g3.Blo[s] = o_wa16; g3.Bhi[s] = o_wbs16;
        g3.bias[s] = o_ba; g3.dst[s] = out_a; g3.mode[s] = 1;
    }
    g3.Blo[1] = o_wb16; g3.Bhi[1] = o_wa16; g3.bias[1] = o_bb; g3.dst[1] = out_b;
    mfma_gemm<2><<<dim3(MROWS/128, 16, 2), 256, 0, stream>>>(g3);
}

// Round 4
// 312.670 us; speedup vs baseline: 1.0066x; 1.0025x over previous
//
#include <hip/hip_runtime.h>
#include <math.h>
#include <stdint.h>

#define BATCH 2
#define SEQ   1024
#define EMB   1024
#define NH    16
#define DH    64
#define BSE   (BATCH*SEQ*EMB)   /* 2097152 elements per (B,S,E) tensor */
#define MROWS (BATCH*SEQ)       /* 2048 */

typedef unsigned short u16;
typedef __attribute__((ext_vector_type(8))) short short8;
typedef __attribute__((ext_vector_type(4))) float f32x4;

__device__ __forceinline__ float bf2f(u16 u) {
    return __uint_as_float(((unsigned int)u) << 16);
}
__device__ __forceinline__ u16 f2bf(float f) {
    unsigned int x = __float_as_uint(f);
    x += 0x7FFFu + ((x >> 16) & 1u);   // round-to-nearest-even
    return (u16)(x >> 16);
}

__device__ __forceinline__ void async_copy16(const void* g, void* l) {
    __builtin_amdgcn_global_load_lds(
        (const __attribute__((address_space(1))) unsigned int*)g,
        (__attribute__((address_space(3))) unsigned int*)l,
        16, 0, 0);
}

#define VMCNT(N)  asm volatile("s_waitcnt vmcnt(" #N ")" ::: "memory")
#define BARRIER_SYNC() do { asm volatile("" ::: "memory"); \
                            __builtin_amdgcn_s_barrier();  \
                            asm volatile("" ::: "memory"); } while (0)
// After-barrier LDS drain: explicit lgkmcnt(0) + sched fence so MFMAs are
// not hoisted above it (rule #18) and start as a clean burst.
#define LGKM0() do { asm volatile("s_waitcnt lgkmcnt(0)" ::: "memory"); \
                     __builtin_amdgcn_sched_barrier(0); } while (0)

// ---------------------------------------------------------------------------
// Pack: fp32 -> bf16, 20 slots of exactly 1M elems each (no idle blocks).
// ---------------------------------------------------------------------------
struct PackArgs {
    const float* src[20];
    u16*         dst[20];
    int          scaled[20];
};

__global__ __launch_bounds__(256) void pack_kernel(PackArgs pa, const float* __restrict__ theta)
{
    const int e = blockIdx.y;
    const size_t i = ((size_t)blockIdx.x * 256 + threadIdx.x) * 4;
    float sc = 1.0f;
    if (pa.scaled[e]) sc = sinf(2.0f * theta[0]) - 1.0f;
    float4 v = *(const float4*)(pa.src[e] + i);
    ushort4 o;
    o.x = f2bf(v.x * sc); o.y = f2bf(v.y * sc);
    o.z = f2bf(v.z * sc); o.w = f2bf(v.w * sc);
    *(ushort4*)(pa.dst[e] + i) = o;
}

// ---------------------------------------------------------------------------
// QKV projection GEMM: 256x256 tile, BK=64, 8 waves, 4 phases/K-tile.
// SEAL INVARIANT (the round-3 NaN fix): every LDS half-tile H is read only
// after a (per-wave vmcnt retiring H -> s_barrier) pair. vmcnt is per-wave,
// so the barrier is what publishes other waves' global_load_lds writes.
//
// Halves: H0=A-lo H1=B-lo H2=B-hi H3=A-hi (2 loads each; H0+H1 issued at p0).
// Steady state per tile kt (buf cur; stages -> buf nxt):
//   p0: read F0(A-lo,B-lo)  stage H0,H1(kt+1)  VMCNT(6)[seals H2(kt)]   bar lgkm0 MFMA q00
//   p1: read F1(B-hi)       stage H2(kt+1)     VMCNT(6)[seals H3(kt)]   bar lgkm0 MFMA q01
//   p2: read F2(A-hi)       stage H3(kt+1)     VMCNT(4)[seals H0,H1(kt+1)] bar lgkm0 MFMA q11
//   p3: register-only MFMA q10 (fa, fb0 live; no reads, no barrier)
// Prologue: stage 4 halves, VMCNT(4)+bar. Peel (tile 31): 2 -> 0 drains,
// each vmcnt followed by a barrier before the dependent reads.
// ---------------------------------------------------------------------------
struct Gemm8Args {
    const u16*   A1s[6];
    const u16*   A2s[6];
    const u16*   Blo[6];
    const u16*   Bhi[6];
    const float* bias[6];
    void*        dst[6];
    int          mode[6];
};

__global__ __launch_bounds__(512, 2) void mfma_gemm8(Gemm8Args ga)
{
    __shared__ u16 lds[2][2][256][64];   // [buf][A/B][row][col] = 128 KiB

    const int t    = threadIdx.x;
    const int lane = t & 63;
    const int w    = t >> 6;
    const int wm   = w >> 2;       // 0..1
    const int wn   = w & 3;        // 0..3
    const int L15  = lane & 15;
    const int quad = lane >> 4;
    const int rswz = L15 & 7;      // read-side chunk swizzle key

    // XCD-aware bijective mapping: XCD x = bid&7 gets nt in [3x,3x+3), all mt.
    const int bid = blockIdx.x;
    const int xcd = bid & 7;
    const int idx = bid >> 3;            // 0..23
    const int nt  = xcd * 3 + (idx >> 3);
    const int mt  = idx & 7;
    const int m0   = mt * 256;
    const int seg  = nt >> 2;
    const int nloc = (nt & 3) * 256;

    const char* A1 = (const char*)ga.A1s[seg];
    const char* A2 = (const char*)ga.A2s[seg];
    const char* Bl = (const char*)ga.Blo[seg];
    const char* Bh = (const char*)ga.Bhi[seg];

    // staging: thread t covers row t>>3 (of a 64-row call), chunk t&7.
    // source chunk pre-swizzled: chunk ^ (row&7); LDS dest stays linear.
    const int   srow8 = t >> 3;
    const int   g16   = (((t & 7) ^ (srow8 & 7)) << 4);
    const char* A1t = A1 + (size_t)(m0   + srow8) * 2048 + g16;
    const char* A2t = A2 + (size_t)(m0   + srow8) * 2048 + g16;
    const char* Blt = Bl + (size_t)(nloc + srow8) * 2048 + g16;
    const char* Bht = Bh + (size_t)(nloc + srow8) * 2048 + g16;
    char* ldsW = (char*)&lds[0][0][0][0] + w * 1024;   // wave's 8-row slab

    auto stage_half = [&](int buf, int mat, const char* srcT, size_t kcol, int r0) {
        #pragma unroll
        for (int c = 0; c < 2; ++c)
            async_copy16(srcT + (size_t)(r0 + c*64) * 2048 + kcol,
                         ldsW + buf*65536 + mat*32768 + (r0 + c*64)*128);
    };

    auto ldA = [&](const u16* Abw, int mq, int m, int ks) -> short8 {
        return *(const short8*)(Abw + (mq*128 + m*16)*64 + (((ks*4 + quad) ^ rswz) << 3));
    };
    auto ldB = [&](const u16* Bbw, int nq, int n, int ks) -> short8 {
        return *(const short8*)(Bbw + (nq*128 + n*16)*64 + (((ks*4 + quad) ^ rswz) << 3));
    };

    f32x4 acc00[4][2] = {};
    f32x4 acc01[4][2] = {};
    f32x4 acc11[4][2] = {};
    f32x4 acc10[4][2] = {};
    short8 fa[4][2];    // A-frags of current m-half
    short8 fb0[2][2];   // B nq=0 (kept across whole tile)
    short8 fb1[2][2];   // B nq=1

    auto readA = [&](const u16* Abw, int mq) {
        #pragma unroll
        for (int m = 0; m < 4; ++m)
            #pragma unroll
            for (int ks = 0; ks < 2; ++ks)
                fa[m][ks] = ldA(Abw, mq, m, ks);
    };
    auto readB = [&](const u16* Bbw, int nq, short8 (&fb)[2][2]) {
        #pragma unroll
        for (int n = 0; n < 2; ++n)
            #pragma unroll
            for (int ks = 0; ks < 2; ++ks)
                fb[n][ks] = ldB(Bbw, nq, n, ks);
    };

    auto mfma4x2 = [&](f32x4 (&accq)[4][2], short8 (&a)[4][2], short8 (&b)[2][2]) {
        __builtin_amdgcn_s_setprio(1);
        #pragma unroll
        for (int m = 0; m < 4; ++m)
            #pragma unroll
            for (int n = 0; n < 2; ++n) {
                accq[m][n] = __builtin_amdgcn_mfma_f32_16x16x32_bf16(a[m][0], b[n][0], accq[m][n], 0, 0, 0);
                accq[m][n] = __builtin_amdgcn_mfma_f32_16x16x32_bf16(a[m][1], b[n][1], accq[m][n], 0, 0, 0);
            }
        __builtin_amdgcn_s_setprio(0);
    };

    // ---- prologue: tile 0 into buf 0 (issue order H0,H1,H2,H3) ----
    stage_half(0, 0, A1t, 0, 0);     // H0 = A-lo
    stage_half(0, 1, Blt, 0, 0);     // H1 = B-lo
    stage_half(0, 1, Blt, 0, 128);   // H2 = B-hi
    stage_half(0, 0, A1t, 0, 128);   // H3 = A-hi
    VMCNT(4);            // seal H0,H1(t0): newest allowed = H2,H3(t0)
    BARRIER_SYNC();

    // ---- main loop: tiles 0..30 steady state, tile 31 peeled ----
    for (int kt = 0; kt < 31; ++kt) {
        const int cur = kt & 1, nxt = cur ^ 1;
        const bool hi = ((kt + 1) & 16) != 0;
        const char* At = hi ? A2t : A1t;
        const char* Bt = hi ? Bht : Blt;
        const size_t kc = (size_t)((kt + 1) & 15) * 128;
        const u16* Abw = &lds[cur][0][wm*64 + L15][0];
        const u16* Bbw = &lds[cur][1][wn*32 + L15][0];

        // ---- p0: quadrant (0,0); F0 sealed by prev VMCNT(4)+bar ----
        readA(Abw, 0);
        readB(Bbw, 0, fb0);
        stage_half(nxt, 0, At, kc, 0);           // H0(kt+1)
        stage_half(nxt, 1, Bt, kc, 0);           // H1(kt+1)
        VMCNT(6);                                 // seal H2(kt)
        BARRIER_SYNC();
        LGKM0();
        mfma4x2(acc00, fa, fb0);

        // ---- p1: quadrant (0,1); F1 = B-hi (H2 of kt) ----
        readB(Bbw, 1, fb1);
        stage_half(nxt, 1, Bt, kc, 128);         // H2(kt+1)
        VMCNT(6);                                 // seal H3(kt)
        BARRIER_SYNC();
        LGKM0();
        mfma4x2(acc01, fa, fb1);

        // ---- p2: quadrant (1,1); F2 = A-hi (H3 of kt) ----
        readA(Abw, 1);
        stage_half(nxt, 0, At, kc, 128);         // H3(kt+1)
        VMCNT(4);                                 // seal H0,H1(kt+1)
        BARRIER_SYNC();
        LGKM0();
        mfma4x2(acc11, fa, fb1);

        // ---- p3: quadrant (1,0); register-only (fa, fb0 live) ----
        mfma4x2(acc10, fa, fb0);
    }

    // ---- peeled last tile (kt=31, buf 1): drains 2 -> 0, sealed ----
    {
        const u16* Abw = &lds[1][0][wm*64 + L15][0];
        const u16* Bbw = &lds[1][1][wn*32 + L15][0];

        readA(Abw, 0);          // H0,H1(31) sealed by loop's last VMCNT(4)+bar
        readB(Bbw, 0, fb0);
        VMCNT(2);               // seal H2(31)
        BARRIER_SYNC();
        LGKM0();
        mfma4x2(acc00, fa, fb0);

        readB(Bbw, 1, fb1);
        VMCNT(0);               // seal H3(31)
        BARRIER_SYNC();
        LGKM0();
        mfma4x2(acc01, fa, fb1);

        readA(Abw, 1);
        LGKM0();
        mfma4x2(acc11, fa, fb1);
        mfma4x2(acc10, fa, fb0);
    }

    // ---- epilogue: C layout col = L15 (+n*16), row = quad*4+reg (+m*16) ----
    const float* bias = ga.bias[seg];
    const int mode = ga.mode[seg];
    u16* dst = (u16*)ga.dst[seg];

    auto store_quad = [&](f32x4 (&accq)[4][2], int mq, int nq) {
        #pragma unroll
        for (int n = 0; n < 2; ++n) {
            const int c = nloc + nq*128 + wn*32 + n*16 + L15;
            const float bv = bias[c];
            #pragma unroll
            for (int m = 0; m < 4; ++m) {
                #pragma unroll
                for (int reg = 0; reg < 4; ++reg) {
                    const int row = m0 + mq*128 + wm*64 + m*16 + quad*4 + reg;
                    const float val = accq[m][n][reg] + bv;
                    if (mode == 2) {
                        // V^T: [b][c][s]
                        dst[((size_t)(row >> 10) << 20) + (size_t)c*1024 + (row & 1023)] = f2bf(val);
                    } else {
                        dst[(size_t)row*1024 + c] = f2bf(val);
                    }
                }
            }
        }
    };
    store_quad(acc00, 0, 0);
    store_quad(acc01, 0, 1);
    store_quad(acc11, 1, 1);
    store_quad(acc10, 1, 0);
}

// ---------------------------------------------------------------------------
// Legacy 128x128 MFMA GEMM (kept for the O-projection, split-K=2).
// ---------------------------------------------------------------------------
struct GemmArgs {
    const u16*   A1s[8];
    const u16*   A2s[8];
    const u16*   Blo[8];
    const u16*   Bhi[8];
    const float* bias[8];
    void*        dst[8];
    int          mode[8];
};

template<int SPLITK>
__global__ __launch_bounds__(256) void mfma_gemm(GemmArgs ga)
{
    __shared__ u16 sA[128][32];
    __shared__ u16 sB[128][32];

    const int t    = threadIdx.x;
    const int lane = t & 63;
    const int w    = t >> 6;
    const int wx   = w & 1;
    const int wy   = w >> 1;
    const int n0   = blockIdx.y * 128;
    const int m0   = blockIdx.x * 128;
    const int ko   = (SPLITK == 2) ? blockIdx.z : 0;
    const int seg  = n0 >> 10;
    const int nloc = n0 & 1023;

    const int srow = t >> 2;
    const int sb   = (t & 3) * 16;

    f32x4 acc[4][4] = {};

    const char* A1 = (const char*)ga.A1s[seg];
    const char* A2 = (const char*)ga.A2s[seg];
    const char* Bl = (const char*)ga.Blo[seg];
    const char* Bh = (const char*)ga.Bhi[seg];
    if (SPLITK == 2 && ko) { A1 = A2; Bl = Bh; }

    const int frow = lane & 15;
    const int quad = lane >> 4;

    const int NKT = (SPLITK == 2) ? 32 : 64;
    for (int kt = 0; kt < NKT; ++kt) {
        const char* As = (SPLITK == 1 && (kt & 32)) ? A2 : A1;
        const char* Bs = (SPLITK == 1 && (kt & 32)) ? Bh : Bl;
        const size_t kbyte = (size_t)(kt & 31) * 64;

        __syncthreads();
        #pragma unroll
        for (int r = 0; r < 2; ++r) {
            const int row = r*64 + srow;
            const int ldsoff = (r*64 + w*16) * 64;
            async_copy16(As + (size_t)(m0 + row)*2048 + kbyte + sb,
                         (char*)&sA[0][0] + ldsoff);
            async_copy16(Bs + (size_t)(nloc + row)*2048 + kbyte + sb,
                         (char*)&sB[0][0] + ldsoff);
        }
        __syncthreads();

        short8 af[4], bfr[4];
        #pragma unroll
        for (int i = 0; i < 4; ++i)
            af[i] = *(const short8*)&sA[wy*64 + i*16 + frow][quad*8];
        #pragma unroll
        for (int j = 0; j < 4; ++j)
            bfr[j] = *(const short8*)&sB[wx*64 + j*16 + frow][quad*8];

        #pragma unroll
        for (int i = 0; i < 4; ++i)
            #pragma unroll
            for (int j = 0; j < 4; ++j)
                acc[i][j] = __builtin_amdgcn_mfma_f32_16x16x32_bf16(
                                af[i], bfr[j], acc[i][j], 0, 0, 0);
    }

    const float* bias = ga.bias[seg];
    const int mode = ga.mode[seg];

    #pragma unroll
    for (int j = 0; j < 4; ++j) {
        const int c = nloc + wx*64 + j*16 + frow;
        const float bv = (SPLITK == 2 && ko) ? 0.0f : bias[c];
        #pragma unroll
        for (int i = 0; i < 4; ++i) {
            #pragma unroll
            for (int reg = 0; reg < 4; ++reg) {
                const int m = m0 + wy*64 + i*16 + quad*4 + reg;
                const float val = acc[i][j][reg] + bv;
                if (mode == 1) {
                    if (SPLITK == 2)
                        atomicAdd((float*)ga.dst[seg] + (size_t)m*1024 + c, val);
                    else
                        ((float*)ga.dst[seg])[(size_t)m*1024 + c] = val;
                } else if (mode == 2) {
                    ((u16*)ga.dst[seg])[((size_t)(m >> 10) << 20) + (size_t)c*1024 + (m & 1023)] = f2bf(val);
                } else {
                    ((u16*)ga.dst[seg])[(size_t)m*1024 + c] = f2bf(val);
                }
            }
        }
    }
}

// ---------------------------------------------------------------------------
// RoPE, in place on (B,S,E) bf16; pair (d, d+32) within each head.
// ---------------------------------------------------------------------------
__global__ __launch_bounds__(256) void rope_kernel(
    u16* qa, u16* qb, u16* ka, u16* kb)
{
    u16* p;
    switch (blockIdx.y) {
        case 0:  p = qa; break;
        case 1:  p = qb; break;
        case 2:  p = ka; break;
        default: p = kb; break;
    }
    const int i   = blockIdx.x * 256 + threadIdx.x;
    const int d   = i & 31;
    const int hh  = (i >> 5) & (NH - 1);
    const int row = i >> 9;
    const int s   = row & (SEQ - 1);
    const size_t base = (size_t)row * EMB + hh * DH;

    float x1 = bf2f(p[base + d]);
    float x2 = bf2f(p[base + d + 32]);
    const float invf_rev = expf(-(float)d * 0.28782313662425576f) * 0.15915494309189535f;
    float rev = (float)s * invf_rev;
    rev -= floorf(rev);
    const float sn = __builtin_amdgcn_sinf(rev);
    const float cs = __builtin_amdgcn_cosf(rev);
    p[base + d]      = f2bf(x1 * cs - x2 * sn);
    p[base + d + 32] = f2bf(x2 * cs + x1 * sn);
}

// ---------------------------------------------------------------------------
// MFMA flash attention, fixed-max softmax.
// ---------------------------------------------------------------------------
__global__ __launch_bounds__(256) void attn_mfma(
    const u16* __restrict__ qa, const u16* __restrict__ qb,
    const u16* __restrict__ ka, const u16* __restrict__ kb,
    const u16* __restrict__ vat, const u16* __restrict__ vbt,
    const float* __restrict__ thetas,
    u16* __restrict__ oa, u16* __restrict__ ob)
{
    __shared__ u16 sKa[64][64];
    __shared__ u16 sKb[64][64];
    __shared__ u16 sVa[64][64];
    __shared__ u16 sVb[64][64];
    __shared__ u16 sP[4][16][72];

    const int t    = threadIdx.x;
    const int lane = t & 63;
    const int w    = t >> 6;
    const int L15  = lane & 15;
    const int quad = lane >> 4;

    const int bid  = blockIdx.x;
    const int aa   = (bid >> 5) & 7;
    const int qt   = (bid >> 8) ? aa : (15 - aa);
    const int bh   = bid & 31;
    const int h    = bh & 15;
    const int b    = bh >> 4;

    const float j2h = sinf(2.0f * thetas[h]) - 1.0f;

    const int   qrow  = qt*64 + w*16 + L15;
    const size_t qbase = (size_t)(b*SEQ + qrow) * EMB + h*DH;
    short8 fqa[2], fqb[2], fjqb[2];
    fqa[0] = *(const short8*)(qa + qbase + quad*8);
    fqa[1] = *(const short8*)(qa + qbase + 32 + quad*8);
    fqb[0] = *(const short8*)(qb + qbase + quad*8);
    fqb[1] = *(const short8*)(qb + qbase + 32 + quad*8);
    #pragma unroll
    for (int s2 = 0; s2 < 2; ++s2) {
        short8 src = fqb[s2], dst;
        #pragma unroll
        for (int j = 0; j < 8; ++j)
            dst[j] = (short)f2bf(bf2f((u16)src[j]) * j2h);
        fjqb[s2] = dst;
    }

    f32x4 acc_a[4] = {};
    f32x4 acc_b[4] = {};
    float l_lane[4] = {0.f, 0.f, 0.f, 0.f};

    const int subrow = lane >> 3;
    const int g      = (lane & 7) ^ subrow;
    const int swz    = L15 & 7;

    for (int kt = 0; kt <= qt; ++kt) {
        __syncthreads();
        #pragma unroll
        for (int i = 0; i < 2; ++i) {
            const int row = w*16 + i*8 + subrow;
            const int ldsoff = (w*16 + i*8) * 128;
            const size_t ktok = (size_t)(b*SEQ + kt*64 + row);
            async_copy16((const char*)ka + ktok*2048 + h*128 + g*16,
                         (char*)&sKa[0][0] + ldsoff);
            async_copy16((const char*)kb + ktok*2048 + h*128 + g*16,
                         (char*)&sKb[0][0] + ldsoff);
            const size_t vrow = (size_t)b*1048576 + (size_t)(h*64 + row)*1024 + kt*64;
            async_copy16((const char*)vat + vrow*2 + g*16,
                         (char*)&sVa[0][0] + ldsoff);
            async_copy16((const char*)vbt + vrow*2 + g*16,
                         (char*)&sVb[0][0] + ldsoff);
        }
        __syncthreads();

        f32x4 sa[4] = {}, sb[4] = {};
        #pragma unroll
        for (int n = 0; n < 4; ++n) {
            const u16* rKa = &sKa[n*16 + L15][0];
            const u16* rKb = &sKb[n*16 + L15][0];
            short8 ka0 = *(const short8*)(rKa + (( quad      ^ swz) << 3));
            short8 ka1 = *(const short8*)(rKa + (((4 + quad) ^ swz) << 3));
            short8 kb0 = *(const short8*)(rKb + (( quad      ^ swz) << 3));
            short8 kb1 = *(const short8*)(rKb + (((4 + quad) ^ swz) << 3));
            sa[n] = __builtin_amdgcn_mfma_f32_16x16x32_bf16(fqa[0],  ka0, sa[n], 0, 0, 0);
            sa[n] = __builtin_amdgcn_mfma_f32_16x16x32_bf16(fqa[1],  ka1, sa[n], 0, 0, 0);
            sa[n] = __builtin_amdgcn_mfma_f32_16x16x32_bf16(fjqb[0], kb0, sa[n], 0, 0, 0);
            sa[n] = __builtin_amdgcn_mfma_f32_16x16x32_bf16(fjqb[1], kb1, sa[n], 0, 0, 0);
            sb[n] = __builtin_amdgcn_mfma_f32_16x16x32_bf16(fqa[0],  kb0, sb[n], 0, 0, 0);
            sb[n] = __builtin_amdgcn_mfma_f32_16x16x32_bf16(fqa[1],  kb1, sb[n], 0, 0, 0);
            sb[n] = __builtin_amdgcn_mfma_f32_16x16x32_bf16(fqb[0],  ka0, sb[n], 0, 0, 0);
            sb[n] = __builtin_amdgcn_mfma_f32_16x16x32_bf16(fqb[1],  ka1, sb[n], 0, 0, 0);
        }

        float p[4][4];
        if (kt == qt) {
            #pragma unroll
            for (int n = 0; n < 4; ++n)
                #pragma unroll
                for (int r = 0; r < 4; ++r) {
                    const float A = sa[n][r], B = sb[n][r];
                    const float mag = __builtin_amdgcn_sqrtf(A*A + B*B + 1e-8f) * 0.125f;
                    const bool masked = (n*16 + L15) > (w*16 + quad*4 + r);
                    p[n][r] = masked ? 0.0f
                                     : __builtin_amdgcn_exp2f(mag * 1.44269504f);
                }
        } else {
            #pragma unroll
            for (int n = 0; n < 4; ++n)
                #pragma unroll
                for (int r = 0; r < 4; ++r) {
                    const float A = sa[n][r], B = sb[n][r];
                    const float mag = __builtin_amdgcn_sqrtf(A*A + B*B + 1e-8f) * 0.125f;
                    p[n][r] = __builtin_amdgcn_exp2f(mag * 1.44269504f);
                }
        }
        #pragma unroll
        for (int r = 0; r < 4; ++r)
            l_lane[r] += (p[0][r] + p[1][r]) + (p[2][r] + p[3][r]);

        #pragma unroll
        for (int n = 0; n < 4; ++n)
            #pragma unroll
            for (int r = 0; r < 4; ++r)
                sP[w][quad*4 + r][n*16 + L15] = f2bf(p[n][r]);

        short8 pf0 = *(const short8*)&sP[w][L15][quad*8];
        short8 pf1 = *(const short8*)&sP[w][L15][32 + quad*8];

        #pragma unroll
        for (int n = 0; n < 4; ++n) {
            const u16* rVa = &sVa[n*16 + L15][0];
            const u16* rVb = &sVb[n*16 + L15][0];
            short8 va0 = *(const short8*)(rVa + (( quad      ^ swz) << 3));
            short8 va1 = *(const short8*)(rVa + (((4 + quad) ^ swz) << 3));
            short8 vb0 = *(const short8*)(rVb + (( quad      ^ swz) << 3));
            short8 vb1 = *(const short8*)(rVb + (((4 + quad) ^ swz) << 3));
            acc_a[n] = __builtin_amdgcn_mfma_f32_16x16x32_bf16(pf0, va0, acc_a[n], 0, 0, 0);
            acc_a[n] = __builtin_amdgcn_mfma_f32_16x16x32_bf16(pf1, va1, acc_a[n], 0, 0, 0);
            acc_b[n] = __builtin_amdgcn_mfma_f32_16x16x32_bf16(pf0, vb0, acc_b[n], 0, 0, 0);
            acc_b[n] = __builtin_amdgcn_mfma_f32_16x16x32_bf16(pf1, vb1, acc_b[n], 0, 0, 0);
        }
    }

    float inv[4];
    #pragma unroll
    for (int r = 0; r < 4; ++r) {
        float l = l_lane[r];
        #pragma unroll
        for (int off = 8; off >= 1; off >>= 1)
            l += __shfl_xor(l, off, 64);
        inv[r] = 1.0f / l;
    }

    #pragma unroll
    for (int reg = 0; reg < 4; ++reg) {
        const size_t tok = (size_t)(b*SEQ + qt*64 + w*16 + quad*4 + reg);
        #pragma unroll
        for (int n = 0; n < 4; ++n) {
            const size_t idx = tok*EMB + h*DH + n*16 + L15;
            oa[idx] = f2bf(acc_a[n][reg] * inv[reg]);
            ob[idx] = f2bf(acc_b[n][reg] * inv[reg]);
        }
    }
}

// ---------------------------------------------------------------------------
extern "C" void kernel_launch(void* const* d_in, const int* in_sizes, int n_in,
                              void* d_out, int out_size, void* d_ws, size_t ws_size,
                              hipStream_t stream)
{
    const float* x_q_a  = (const float*)d_in[0];
    const float* x_q_b  = (const float*)d_in[1];
    const float* x_kv_a = (const float*)d_in[2];
    const float* x_kv_b = (const float*)d_in[3];
    const float* theta    = (const float*)d_in[5];
    const float* thetas_h = (const float*)d_in[6];
    const float* q_wa = (const float*)d_in[7];
    const float* q_wb = (const float*)d_in[8];
    const float* q_ba = (const float*)d_in[9];
    const float* q_bb = (const float*)d_in[10];
    const float* k_wa = (const float*)d_in[11];
    const float* k_wb = (const float*)d_in[12];
    const float* k_ba = (const float*)d_in[13];
    const float* k_bb = (const float*)d_in[14];
    const float* v_wa = (const float*)d_in[15];
    const float* v_wb = (const float*)d_in[16];
    const float* v_ba = (const float*)d_in[17];
    const float* v_bb = (const float*)d_in[18];
    const float* o_wa = (const float*)d_in[19];
    const float* o_wb = (const float*)d_in[20];
    const float* o_ba = (const float*)d_in[21];
    const float* o_bb = (const float*)d_in[22];

    u16* W = (u16*)d_ws;
    const size_t XN = (size_t)BSE;
    const size_t WN = (size_t)EMB*EMB;
    u16* xq_a16  = W;
    u16* xq_b16  = W + XN;
    u16* xkv_a16 = W + 2*XN;
    u16* xkv_b16 = W + 3*XN;
    u16* wbase   = W + 4*XN;
    u16* q_wa16  = wbase;
    u16* q_wb16  = wbase + WN;
    u16* k_wa16  = wbase + 2*WN;
    u16* k_wb16  = wbase + 3*WN;
    u16* v_wa16  = wbase + 4*WN;
    u16* v_wb16  = wbase + 5*WN;
    u16* o_wa16  = wbase + 6*WN;
    u16* o_wb16  = wbase + 7*WN;
    u16* q_wbs16 = wbase + 8*WN;
    u16* k_wbs16 = wbase + 9*WN;
    u16* v_wbs16 = wbase + 10*WN;
    u16* o_wbs16 = wbase + 11*WN;
    u16* qkv     = wbase + 12*WN;
    u16* qa16 = qkv;
    u16* qb16 = qkv + XN;
    u16* ka16 = qkv + 2*XN;
    u16* kb16 = qkv + 3*XN;
    u16* vat16 = qkv + 4*XN;   // transposed [b][c][s]
    u16* vbt16 = qkv + 5*XN;
    u16* ao16 = xq_a16;        // alias: xq region free after QKV GEMM
    u16* bo16 = xq_b16;

    float* out_a = (float*)d_out;
    float* out_b = out_a + (size_t)BSE;

    // ---- 1. pack to bf16 ----
    PackArgs pa;
    int si = 0;
    auto add = [&](const float* s, u16* d, int scaled, int chunks) {
        for (int c = 0; c < chunks; ++c) {
            pa.src[si] = s + (size_t)c * WN;
            pa.dst[si] = d + (size_t)c * WN;
            pa.scaled[si] = scaled;
            ++si;
        }
    };
    add(x_q_a,  xq_a16,  0, 2);
    add(x_q_b,  xq_b16,  0, 2);
    add(x_kv_a, xkv_a16, 0, 2);
    add(x_kv_b, xkv_b16, 0, 2);
    add(q_wa, q_wa16, 0, 1);  add(q_wb, q_wb16, 0, 1);
    add(k_wa, k_wa16, 0, 1);  add(k_wb, k_wb16, 0, 1);
    add(v_wa, v_wa16, 0, 1);  add(v_wb, v_wb16, 0, 1);
    add(o_wa, o_wa16, 0, 1);  add(o_wb, o_wb16, 0, 1);
    add(q_wb, q_wbs16, 1, 1); add(k_wb, k_wbs16, 1, 1);
    add(v_wb, v_wbs16, 1, 1); add(o_wb, o_wbs16, 1, 1);
    pack_kernel<<<dim3(WN/1024, 20), 256, 0, stream>>>(pa, theta);

    hipMemsetAsync(d_out, 0, (size_t)out_size * sizeof(float), stream);

    // ---- 2. QKV projections: 256x256 sealed-pipeline kernel, 24 n-tiles ----
    Gemm8Args g8;
    {
        const u16* a1s[6] = { xq_a16, xq_a16, xkv_a16, xkv_a16, xkv_a16, xkv_a16 };
        const u16* a2s[6] = { xq_b16, xq_b16, xkv_b16, xkv_b16, xkv_b16, xkv_b16 };
        const u16* blo[6] = { q_wa16, q_wb16, k_wa16, k_wb16, v_wa16, v_wb16 };
        const u16* bhi[6] = { q_wbs16, q_wa16, k_wbs16, k_wa16, v_wbs16, v_wa16 };
        const float* bia[6] = { q_ba, q_bb, k_ba, k_bb, v_ba, v_bb };
        void* dsts[6] = { qa16, qb16, ka16, kb16, vat16, vbt16 };
        const int modes[6] = { 0, 0, 0, 0, 2, 2 };
        for (int s = 0; s < 6; ++s) {
            g8.A1s[s] = a1s[s]; g8.A2s[s] = a2s[s];
            g8.Blo[s] = blo[s]; g8.Bhi[s] = bhi[s];
            g8.bias[s] = bia[s]; g8.dst[s] = dsts[s]; g8.mode[s] = modes[s];
        }
    }
    mfma_gemm8<<<dim3(192), 512, 0, stream>>>(g8);

    // ---- 3. RoPE (q/k) ----
    rope_kernel<<<dim3((BATCH*SEQ*NH*32)/256, 4), 256, 0, stream>>>(qa16, qb16, ka16, kb16);

    // ---- 4. attention ----
    attn_mfma<<<BATCH*NH*(SEQ/64), 256, 0, stream>>>(qa16, qb16, ka16, kb16,
                                                     vat16, vbt16, thetas_h, ao16, bo16);

    // ---- 5. output projection: split-K=2, fp32 atomic accumulation ----
    GemmArgs g3;
    for (int s = 0; s < 8; ++s) {
        g3.A1s[s] = ao16; g3.A2s[s] = bo16;
        g3.Blo[s] = o_wa16; g3.Bhi[s] = o_wbs16;
        g3.bias[s] = o_ba; g3.dst[s] = out_a; g3.mode[s] = 1;
    }
    g3.Blo[1] = o_wb16; g3.Bhi[1] = o_wa16; g3.bias[1] = o_bb; g3.dst[1] = out_b;
    mfma_gemm<2><<<dim3(MROWS/128, 16, 2), 256, 0, stream>>>(g3);
}